// Round 9
// baseline (199.656 us; speedup 1.0000x reference)
//
#include <hip/hip_runtime.h>
#include <hip/hip_bf16.h>

typedef __attribute__((ext_vector_type(4))) float f32x4;
typedef __attribute__((ext_vector_type(8))) short bf16x8;

#define H 1024        // hidden / K
#define NTOT 1280     // nq*64 + nkv*64*2
#define BM 256
#define BN 256
#define BK 64
#define NKT 16        // H / BK
#define NTILES 5      // NTOT / BN

static __device__ __forceinline__ unsigned short f2bf(float f) {
    __hip_bfloat16 b = __float2bfloat16(f);
    return __builtin_bit_cast(unsigned short, b);
}

#define GLOAD_LDS16(g, l)                                                     \
    __builtin_amdgcn_global_load_lds(                                         \
        (const __attribute__((address_space(1))) void*)(g),                   \
        (__attribute__((address_space(3))) void*)(l), 16, 0, 0)

// ---------------------------------------------------------------------------
// Kernel 1: RMSNorm rows of x (fp32) -> h (bf16). One wave per row.
// ---------------------------------------------------------------------------
__global__ __launch_bounds__(256) void k_rms(const float* __restrict__ x,
                                             __hip_bfloat16* __restrict__ h) {
    const int wave = threadIdx.x >> 6;
    const int lane = threadIdx.x & 63;
    const size_t row = (size_t)blockIdx.x * 4 + wave;

    const float4* xr = (const float4*)(x + row * H);
    float4 v[4];
    float ss = 0.f;
#pragma unroll
    for (int i = 0; i < 4; ++i) {
        v[i] = xr[lane + 64 * i];
        ss += v[i].x * v[i].x + v[i].y * v[i].y + v[i].z * v[i].z + v[i].w * v[i].w;
    }
#pragma unroll
    for (int o = 1; o < 64; o <<= 1) ss += __shfl_xor(ss, o);
    const float sc = rsqrtf(ss * (1.0f / H) + 1e-6f);

    ushort4* hr = (ushort4*)(h + row * H);
#pragma unroll
    for (int i = 0; i < 4; ++i) {
        ushort4 o4;
        o4.x = f2bf(v[i].x * sc);
        o4.y = f2bf(v[i].y * sc);
        o4.z = f2bf(v[i].z * sc);
        o4.w = f2bf(v[i].w * sc);
        hr[lane + 64 * i] = o4;
    }
}

// ---------------------------------------------------------------------------
// Kernel 2: Bt[n][k] = bf16((1+lnw[k]) * W[k][n]) via LDS transpose tile.
// ---------------------------------------------------------------------------
__global__ __launch_bounds__(256) void k_wprep(const float* __restrict__ wq,
                                               const float* __restrict__ wk,
                                               const float* __restrict__ wv,
                                               const float* __restrict__ lnw,
                                               __hip_bfloat16* __restrict__ Bt) {
    __shared__ float l[64][65];
    const int t = threadIdx.x;
    const int kt = blockIdx.x & 15;          // 16 k-tiles
    const int ntl = blockIdx.x >> 4;         // 20 n-tiles
    const int k0 = kt * 64, n0 = ntl * 64;
    const float* src; int ldn, nb;
    if (n0 < 1024)      { src = wq; ldn = 1024; nb = n0; }
    else if (n0 < 1152) { src = wk; ldn = 128;  nb = n0 - 1024; }
    else                { src = wv; ldn = 128;  nb = n0 - 1152; }
    const int nl = t & 63, kl = t >> 6;
#pragma unroll
    for (int i = 0; i < 16; ++i) {
        const int k = kl + i * 4;
        l[k][nl] = (1.0f + lnw[k0 + k]) * src[(size_t)(k0 + k) * ldn + nb + nl];
    }
    __syncthreads();
    const int k2 = t & 63, n2 = t >> 6;
#pragma unroll
    for (int i = 0; i < 16; ++i) {
        const int n = n2 + i * 4;
        Bt[(size_t)(n0 + n) * 1024 + k0 + k2] = __float2bfloat16(l[k2][n]);
    }
}

// ---------------------------------------------------------------------------
// Kernel 3: GEMM out[M][1280] = h[M][1024] @ Bt^T.
// R9: B OUT OF LDS. Analysis R2-R8: LDS frag-read traffic (196KB/K-tile/CU ~
// 1800-2300cyc) ~= MFMA floor (2065cyc) -> barrier-pinned phases serialize
// them at ~31% MfmaUtil forever. Fix: A stays in LDS (gload_lds + T2 swizzle,
// 128KB/tile ~1200-1500cyc); B-frags load global->VGPR directly (Bt is 2.6MB,
// L2/L1-resident, no swizzle needed), double-buffered in registers, issued a
// full K-tile ahead (~1100cyc lead >> L2 latency). One barrier per K-tile so
// the 2 waves/SIMD drift and overlap ds_read/MFMA. 256x256 tile, 8 waves
// (2Mx4N, per-wave 128x64), acc[8][4]=128 AGPR + bA/bB 64 + af 32 ~= 240/256.
// ---------------------------------------------------------------------------
__global__ __launch_bounds__(512, 2) void k_gemm(const __hip_bfloat16* __restrict__ A,
                                                 const __hip_bfloat16* __restrict__ Bt,
                                                 float* __restrict__ out, int rows) {
    __shared__ __align__(16) char smem[65536];  // 2 bufs x A 32KB

    const int tid = threadIdx.x;
    const int lane = tid & 63;
    const int wid = tid >> 6;
    const int wm = wid >> 2;   // 0..1 (128 rows each)
    const int wn = wid & 3;    // 0..3 (64 cols each)

    // bijective XCD chunk swizzle (640 % 8 == 0), nt fastest
    const int cpx = gridDim.x >> 3;                 // 80
    const int wg = (blockIdx.x & 7) * cpx + (blockIdx.x >> 3);
    const int nt = wg % NTILES;
    const int mt = wg / NTILES;
    const size_t m0 = (size_t)mt * BM;

    // ---- A staging: thread t covers row (t>>3)+q*64, 16B at (t&7)*16,
    //      source col pre-swizzled by ((row&7)<<4) (both-sides involution)
    const int cswz = ((tid & 7) * 16) ^ (((tid >> 3) & 7) << 4);
    const char* aG = (const char*)A + (m0 + (tid >> 3)) * (size_t)(H * 2) + cswz;

#define STAGE_A(buf, kt)                                                      \
    _Pragma("unroll") for (int q = 0; q < 4; ++q)                             \
        GLOAD_LDS16(aG + (size_t)(kt) * 128 + (size_t)q * 64 * (H * 2),       \
                    smem + (buf) * 32768 + q * 8192 + tid * 16);

    // ---- B direct global->reg: lane reads row nt*256+wn*64+(lane&15)+ni*16,
    //      k elems (lane>>4)*8 + kk*32 + kt*64  (same data the LDS path fed)
    const short* bGr = (const short*)Bt
        + ((size_t)nt * BN + wn * 64 + (lane & 15)) * (size_t)H
        + (lane >> 4) * 8;

#define BLOAD(dst, kt)                                                        \
    _Pragma("unroll") for (int ni = 0; ni < 4; ++ni)                          \
        _Pragma("unroll") for (int kk = 0; kk < 2; ++kk)                      \
            dst[ni * 2 + kk] = *(const bf16x8*)(bGr + ni * 16 * H + kk * 32   \
                                                + (size_t)(kt) * 64);

    // ---- A fragment read addressing (swizzled) ----
    const int rowA = wm * 128 + (lane & 15);
    const int xm = (lane & 7) << 4;
    const int c0 = (((lane >> 4) * 16)) ^ xm;
    const int c1 = (64 + ((lane >> 4) * 16)) ^ xm;

    f32x4 acc[8][4] = {};

#define TILE(cur, kt, BN_, DS_, bcur, bnext)                                  \
    {                                                                         \
        if (BN_) BLOAD(bnext, (kt) + 1);                                      \
        const char* aL = smem + (cur) * 32768;                                \
        bf16x8 af[8];                                                         \
        _Pragma("unroll") for (int mi = 0; mi < 8; ++mi)                      \
            af[mi] = *(const bf16x8*)(aL + (rowA + mi * 16) * 128 + c0);      \
        asm volatile("s_waitcnt lgkmcnt(0)" ::: "memory");                    \
        __builtin_amdgcn_s_setprio(1);                                        \
        _Pragma("unroll") for (int mi = 0; mi < 8; ++mi)                      \
            _Pragma("unroll") for (int ni = 0; ni < 4; ++ni)                  \
                acc[mi][ni] = __builtin_amdgcn_mfma_f32_16x16x32_bf16(        \
                    af[mi], bcur[ni * 2 + 0], acc[mi][ni], 0, 0, 0);          \
        __builtin_amdgcn_s_setprio(0);                                        \
        _Pragma("unroll") for (int mi = 0; mi < 8; ++mi)                      \
            af[mi] = *(const bf16x8*)(aL + (rowA + mi * 16) * 128 + c1);      \
        asm volatile("s_waitcnt lgkmcnt(0)" ::: "memory");                    \
        __builtin_amdgcn_s_setprio(1);                                        \
        _Pragma("unroll") for (int mi = 0; mi < 8; ++mi)                      \
            _Pragma("unroll") for (int ni = 0; ni < 4; ++ni)                  \
                acc[mi][ni] = __builtin_amdgcn_mfma_f32_16x16x32_bf16(        \
                    af[mi], bcur[ni * 2 + 1], acc[mi][ni], 0, 0, 0);          \
        __builtin_amdgcn_s_setprio(0);                                        \
        asm volatile("s_waitcnt vmcnt(0)" ::: "memory");                      \
        __builtin_amdgcn_sched_barrier(0);                                    \
        __builtin_amdgcn_s_barrier();                                         \
        __builtin_amdgcn_sched_barrier(0);                                    \
        if (DS_) STAGE_A(cur, (kt) + 2);                                      \
    }

    // ---- prologue ----
    bf16x8 bA[8], bB[8];
    STAGE_A(0, 0);
    STAGE_A(1, 1);
    BLOAD(bA, 0);
    asm volatile("s_waitcnt vmcnt(0)" ::: "memory");
    __builtin_amdgcn_sched_barrier(0);
    __builtin_amdgcn_s_barrier();
    __builtin_amdgcn_sched_barrier(0);

    // ---- main loop: one barrier per K-tile, ring-2 A, reg-dbuf B ----
    for (int kt = 0; kt < 12; kt += 2) {
        TILE(0, kt, 1, 1, bA, bB);
        TILE(1, kt + 1, 1, 1, bB, bA);
    }
    TILE(0, 12, 1, 1, bA, bB);   // loads B(13), stages A(14)
    TILE(1, 13, 1, 1, bB, bA);   // loads B(14), stages A(15)
    TILE(0, 14, 1, 0, bA, bB);   // loads B(15)
    TILE(1, 15, 0, 0, bB, bA);

    // ---- epilogue: split q/k/v regions (wn*64 never straddles boundaries) ----
    const size_t QSZ = (size_t)rows * 1024;
    const size_t KSZ = (size_t)rows * 128;
    const int colg0 = nt * BN + wn * 64;
    float* op;
    int ldc, cb0;
    if (colg0 < 1024)      { op = out;             ldc = 1024; cb0 = colg0; }
    else if (colg0 < 1152) { op = out + QSZ;       ldc = 128;  cb0 = colg0 - 1024; }
    else                   { op = out + QSZ + KSZ; ldc = 128;  cb0 = colg0 - 1152; }

    const size_t r0 = m0 + wm * 128 + ((lane >> 4) * 4);
    const int cc0 = cb0 + (lane & 15);
#pragma unroll
    for (int mi = 0; mi < 8; ++mi)
#pragma unroll
        for (int ni = 0; ni < 4; ++ni)
#pragma unroll
            for (int r = 0; r < 4; ++r)
                op[(r0 + mi * 16 + r) * (size_t)ldc + cc0 + ni * 16] = acc[mi][ni][r];
}

// ---------------------------------------------------------------------------
extern "C" void kernel_launch(void* const* d_in, const int* in_sizes, int n_in,
                              void* d_out, int out_size, void* d_ws, size_t ws_size,
                              hipStream_t stream) {
    const float* x   = (const float*)d_in[0];
    const float* lnw = (const float*)d_in[1];
    const float* wq  = (const float*)d_in[2];
    const float* wk  = (const float*)d_in[3];
    const float* wv  = (const float*)d_in[4];
    float* out = (float*)d_out;

    const int rows = in_sizes[0] / H;  // B*S = 32768

    __hip_bfloat16* Bt = (__hip_bfloat16*)d_ws;                               // 2.62 MB
    __hip_bfloat16* h  = (__hip_bfloat16*)((char*)d_ws + (size_t)NTOT * H * 2);

    k_wprep<<<320, 256, 0, stream>>>(wq, wk, wv, lnw, Bt);
    k_rms<<<rows / 4, 256, 0, stream>>>(x, h);
    k_gemm<<<(rows / BM) * NTILES, 512, 0, stream>>>(h, Bt, out, rows);
}

// Round 10
// 142.637 us; speedup vs baseline: 1.3998x; 1.3998x over previous
//
#include <hip/hip_runtime.h>
#include <hip/hip_bf16.h>

typedef __attribute__((ext_vector_type(4))) float f32x4;
typedef __attribute__((ext_vector_type(8))) short bf16x8;

#define H 1024        // hidden / K
#define NTOT 1280     // nq*64 + nkv*64*2
#define BM 128
#define BN 128
#define BK 64
#define NKT 16        // H / BK
#define NTILES 10     // NTOT / BN

static __device__ __forceinline__ unsigned short f2bf(float f) {
    __hip_bfloat16 b = __float2bfloat16(f);
    return __builtin_bit_cast(unsigned short, b);
}

#define GLOAD_LDS16(g, l)                                                     \
    __builtin_amdgcn_global_load_lds(                                         \
        (const __attribute__((address_space(1))) void*)(g),                   \
        (__attribute__((address_space(3))) void*)(l), 16, 0, 0)

// ---------------------------------------------------------------------------
// Kernel 1: RMSNorm rows of x (fp32) -> h (bf16). One wave per row.
// ---------------------------------------------------------------------------
__global__ __launch_bounds__(256) void k_rms(const float* __restrict__ x,
                                             __hip_bfloat16* __restrict__ h) {
    const int wave = threadIdx.x >> 6;
    const int lane = threadIdx.x & 63;
    const size_t row = (size_t)blockIdx.x * 4 + wave;

    const float4* xr = (const float4*)(x + row * H);
    float4 v[4];
    float ss = 0.f;
#pragma unroll
    for (int i = 0; i < 4; ++i) {
        v[i] = xr[lane + 64 * i];
        ss += v[i].x * v[i].x + v[i].y * v[i].y + v[i].z * v[i].z + v[i].w * v[i].w;
    }
#pragma unroll
    for (int o = 1; o < 64; o <<= 1) ss += __shfl_xor(ss, o);
    const float sc = rsqrtf(ss * (1.0f / H) + 1e-6f);

    ushort4* hr = (ushort4*)(h + row * H);
#pragma unroll
    for (int i = 0; i < 4; ++i) {
        ushort4 o4;
        o4.x = f2bf(v[i].x * sc);
        o4.y = f2bf(v[i].y * sc);
        o4.z = f2bf(v[i].z * sc);
        o4.w = f2bf(v[i].w * sc);
        hr[lane + 64 * i] = o4;
    }
}

// ---------------------------------------------------------------------------
// Kernel 2: Bt[n][k] = bf16((1+lnw[k]) * W[k][n]) via LDS transpose tile.
// ---------------------------------------------------------------------------
__global__ __launch_bounds__(256) void k_wprep(const float* __restrict__ wq,
                                               const float* __restrict__ wk,
                                               const float* __restrict__ wv,
                                               const float* __restrict__ lnw,
                                               __hip_bfloat16* __restrict__ Bt) {
    __shared__ float l[64][65];
    const int t = threadIdx.x;
    const int kt = blockIdx.x & 15;          // 16 k-tiles
    const int ntl = blockIdx.x >> 4;         // 20 n-tiles
    const int k0 = kt * 64, n0 = ntl * 64;
    const float* src; int ldn, nb;
    if (n0 < 1024)      { src = wq; ldn = 1024; nb = n0; }
    else if (n0 < 1152) { src = wk; ldn = 128;  nb = n0 - 1024; }
    else                { src = wv; ldn = 128;  nb = n0 - 1152; }
    const int nl = t & 63, kl = t >> 6;
#pragma unroll
    for (int i = 0; i < 16; ++i) {
        const int k = kl + i * 4;
        l[k][nl] = (1.0f + lnw[k0 + k]) * src[(size_t)(k0 + k) * ldn + nb + nl];
    }
    __syncthreads();
    const int k2 = t & 63, n2 = t >> 6;
#pragma unroll
    for (int i = 0; i < 16; ++i) {
        const int n = n2 + i * 4;
        Bt[(size_t)(n0 + n) * 1024 + k0 + k2] = __float2bfloat16(l[k2][n]);
    }
}

// ---------------------------------------------------------------------------
// Kernel 3: GEMM out[M][1280] = h[M][1024] @ Bt^T.
// R10: OCCUPANCY, not schedule. All single-block schedules pinned at ~31%
// MfmaUtil because LDS pipe (~40k cyc/block) + MFMA (33k) + epilogue HBM
// (26k) SERIALIZE under block-wide barriers at 1 block/CU. Fix: 256-thread
// blocks (4 waves, 2x2), BM=BN=128, 64KB LDS ring-2, acc[4][4]=64 AGPR,
// ~120 VGPR -> TWO independent blocks per CU. No shared barriers between
// them: one block's MFMA overlaps the other's staging/epilogue. setprio
// arbitrates between co-resident blocks (m191 regime). R2-proven 2-barrier
// loop, counted vmcnt(8), T2 both-sides swizzle, XCD chunking nt-fastest.
// Grid 2560 = 5 rounds of 512 co-resident.
// ---------------------------------------------------------------------------
__global__ __launch_bounds__(256, 2) void k_gemm(const __hip_bfloat16* __restrict__ A,
                                                 const __hip_bfloat16* __restrict__ Bt,
                                                 float* __restrict__ out, int rows) {
    __shared__ __align__(16) char smem[65536];  // 2 bufs x (A 16KB | B 16KB)

    const int tid = threadIdx.x;
    const int lane = tid & 63;
    const int wid = tid >> 6;
    const int wm = wid >> 1;   // 0..1 (64 rows each)
    const int wn = wid & 1;    // 0..1 (64 cols each)

    // bijective XCD chunk swizzle (2560 % 8 == 0), nt fastest
    const int cpx = gridDim.x >> 3;                 // 320
    const int wg = (blockIdx.x & 7) * cpx + (blockIdx.x >> 3);
    const int nt = wg % NTILES;
    const int mt = wg / NTILES;
    const size_t m0 = (size_t)mt * BM;

    // staging: thread t covers row (t>>3)+q*32 (q=0..3), 16B at (t&7)*16,
    // source col pre-swizzled by ((row&7)<<4)  (both-sides involution)
    const int r = tid >> 3;                         // 0..31
    const int cswz = ((tid & 7) * 16) ^ ((r & 7) << 4);
    const char* aG = (const char*)A + (m0 + r) * (size_t)(H * 2) + cswz;
    const char* bG = (const char*)Bt + ((size_t)nt * BN + r) * (size_t)(H * 2) + cswz;

#define STAGE(buf, kt)                                                        \
    {                                                                         \
        _Pragma("unroll") for (int q = 0; q < 4; ++q)                         \
            GLOAD_LDS16(aG + (size_t)(kt) * 128 + (size_t)q * 32 * (H * 2),   \
                        smem + (buf) * 32768 + q * 4096 + tid * 16);          \
        _Pragma("unroll") for (int q = 0; q < 4; ++q)                         \
            GLOAD_LDS16(bG + (size_t)(kt) * 128 + (size_t)q * 32 * (H * 2),   \
                        smem + (buf) * 32768 + 16384 + q * 4096 + tid * 16);  \
    }

    // fragment read addressing (swizzled)
    const int rowA = wm * 64 + (lane & 15);
    const int rowB = wn * 64 + (lane & 15);
    const int xm = (lane & 7) << 4;
    const int c0 = (((lane >> 4) * 16)) ^ xm;
    const int c1 = (64 + ((lane >> 4) * 16)) ^ xm;

    f32x4 acc[4][4] = {};

#define TILE(cur, kt, DS, VM)                                                 \
    {                                                                         \
        const char* aL = smem + (cur) * 32768;                                \
        const char* bL = aL + 16384;                                          \
        asm volatile("s_waitcnt vmcnt(" VM ")" ::: "memory");                 \
        __builtin_amdgcn_s_barrier();                                         \
        bf16x8 a0[4], b0[4];                                                  \
        _Pragma("unroll") for (int mi = 0; mi < 4; ++mi)                      \
            a0[mi] = *(const bf16x8*)(aL + (rowA + mi * 16) * 128 + c0);      \
        _Pragma("unroll") for (int ni = 0; ni < 4; ++ni)                      \
            b0[ni] = *(const bf16x8*)(bL + (rowB + ni * 16) * 128 + c0);      \
        __builtin_amdgcn_s_setprio(1);                                        \
        _Pragma("unroll") for (int mi = 0; mi < 4; ++mi)                      \
            _Pragma("unroll") for (int ni = 0; ni < 4; ++ni)                  \
                acc[mi][ni] = __builtin_amdgcn_mfma_f32_16x16x32_bf16(        \
                    a0[mi], b0[ni], acc[mi][ni], 0, 0, 0);                    \
        __builtin_amdgcn_s_setprio(0);                                        \
        bf16x8 a1[4], b1[4];                                                  \
        _Pragma("unroll") for (int mi = 0; mi < 4; ++mi)                      \
            a1[mi] = *(const bf16x8*)(aL + (rowA + mi * 16) * 128 + c1);      \
        _Pragma("unroll") for (int ni = 0; ni < 4; ++ni)                      \
            b1[ni] = *(const bf16x8*)(bL + (rowB + ni * 16) * 128 + c1);      \
        asm volatile("s_waitcnt lgkmcnt(0)" ::: "memory");                    \
        __builtin_amdgcn_sched_barrier(0);                                    \
        __builtin_amdgcn_s_barrier();                                         \
        __builtin_amdgcn_sched_barrier(0);                                    \
        if (DS) STAGE(cur, (kt) + 2);                                         \
        __builtin_amdgcn_s_setprio(1);                                        \
        _Pragma("unroll") for (int mi = 0; mi < 4; ++mi)                      \
            _Pragma("unroll") for (int ni = 0; ni < 4; ++ni)                  \
                acc[mi][ni] = __builtin_amdgcn_mfma_f32_16x16x32_bf16(        \
                    a1[mi], b1[ni], acc[mi][ni], 0, 0, 0);                    \
        __builtin_amdgcn_s_setprio(0);                                        \
    }

    // prologue: stage tiles 0 and 1
    STAGE(0, 0);
    STAGE(1, 1);

    // main loop: ring-2, 2 barriers/tile, loads never drained mid-loop
    for (int kt = 0; kt < NKT - 4; kt += 2) {
        TILE(0, kt, 1, "8");
        TILE(1, kt + 1, 1, "8");
    }
    TILE(0, NKT - 4, 1, "8");   // stages tile 14
    TILE(1, NKT - 3, 1, "8");   // stages tile 15
    TILE(0, NKT - 2, 0, "8");
    TILE(1, NKT - 1, 0, "0");

    // epilogue: split q/k/v regions (wn*64 chunks never straddle boundaries)
    const size_t QSZ = (size_t)rows * 1024;
    const size_t KSZ = (size_t)rows * 128;
    const int colg0 = nt * BN + wn * 64;
    float* op;
    int ldc, cb0;
    if (colg0 < 1024)      { op = out;             ldc = 1024; cb0 = colg0; }
    else if (colg0 < 1152) { op = out + QSZ;       ldc = 128;  cb0 = colg0 - 1024; }
    else                   { op = out + QSZ + KSZ; ldc = 128;  cb0 = colg0 - 1152; }

    const size_t r0 = m0 + wm * 64 + ((lane >> 4) * 4);
    const int cc0 = cb0 + (lane & 15);
#pragma unroll
    for (int mi = 0; mi < 4; ++mi)
#pragma unroll
        for (int ni = 0; ni < 4; ++ni)
#pragma unroll
            for (int rr = 0; rr < 4; ++rr)
                op[(r0 + mi * 16 + rr) * (size_t)ldc + cc0 + ni * 16] = acc[mi][ni][rr];
}

// ---------------------------------------------------------------------------
extern "C" void kernel_launch(void* const* d_in, const int* in_sizes, int n_in,
                              void* d_out, int out_size, void* d_ws, size_t ws_size,
                              hipStream_t stream) {
    const float* x   = (const float*)d_in[0];
    const float* lnw = (const float*)d_in[1];
    const float* wq  = (const float*)d_in[2];
    const float* wk  = (const float*)d_in[3];
    const float* wv  = (const float*)d_in[4];
    float* out = (float*)d_out;

    const int rows = in_sizes[0] / H;  // B*S = 32768

    __hip_bfloat16* Bt = (__hip_bfloat16*)d_ws;                               // 2.62 MB
    __hip_bfloat16* h  = (__hip_bfloat16*)((char*)d_ws + (size_t)NTOT * H * 2);

    k_wprep<<<320, 256, 0, stream>>>(wq, wk, wv, lnw, Bt);
    k_rms<<<rows / 4, 256, 0, stream>>>(x, h);
    k_gemm<<<(rows / BM) * NTILES, 256, 0, stream>>>(h, Bt, out, rows);
}